// Round 1
// baseline (391.398 us; speedup 1.0000x reference)
//
#include <hip/hip_runtime.h>

// Problem constants (verified against in_sizes at launch):
//   v: [E, 64, 3] f32, k: [E, 8, 16] f32, q: [N, 8, 16] f32, dst: [E] i32
//   out: [N, 64, 3] f32.  H=8 heads, T=16, 8 value channels/head, D=3.
#define HH 8
#define TT 16
#define CAP 256   // LDS edge-id cache per wave (max degree ~48 for Poisson(16))

static constexpr float SCALE = 0.08838834764831843f;  // 1/sqrt(8*16)

// Pass 1: logits[e,h] = scale * dot(k[e,h,:], q[dst[e],h,:]); degree histogram.
__global__ __launch_bounds__(256) void logits_kernel(
    const float* __restrict__ k, const float* __restrict__ q,
    const int* __restrict__ dst, float* __restrict__ logits,
    int* __restrict__ deg, int E) {
  int tid = blockIdx.x * blockDim.x + threadIdx.x;
  if (tid >= E * HH) return;
  int e = tid >> 3;
  int h = tid & 7;
  int d = dst[e];
  const float4* kk = (const float4*)(k + (size_t)e * (HH * TT) + h * TT);
  const float4* qq = (const float4*)(q + (size_t)d * (HH * TT) + h * TT);
  float acc = 0.f;
#pragma unroll
  for (int i = 0; i < 4; ++i) {
    float4 a = kk[i];
    float4 b = qq[i];
    acc += a.x * b.x + a.y * b.y + a.z * b.z + a.w * b.w;
  }
  logits[tid] = acc * SCALE;
  if (h == 0) atomicAdd(&deg[d], 1);
}

// Pass 2: exclusive scan of degrees -> CSR offsets. Single block, 1024 threads.
__global__ __launch_bounds__(1024) void scan_kernel(
    const int* __restrict__ deg, int* __restrict__ offs, int N) {
  __shared__ int sm[1024];
  int t = threadIdx.x;
  int chunk = (N + 1023) / 1024;
  int lo = t * chunk;
  int hi = min(lo + chunk, N);
  int s = 0;
  for (int i = lo; i < hi; ++i) s += deg[i];
  sm[t] = s;
  __syncthreads();
  for (int off = 1; off < 1024; off <<= 1) {
    int x = (t >= off) ? sm[t - off] : 0;
    __syncthreads();
    sm[t] += x;
    __syncthreads();
  }
  int run = (t > 0) ? sm[t - 1] : 0;
  for (int i = lo; i < hi; ++i) {
    offs[i] = run;
    run += deg[i];
  }
  if (t == 1023) offs[N] = sm[1023];
}

// Pass 3: scatter edge ids into CSR order.
__global__ __launch_bounds__(256) void fill_kernel(
    const int* __restrict__ dst, const int* __restrict__ offs,
    int* __restrict__ cursor, int* __restrict__ eid, int E) {
  int e = blockIdx.x * blockDim.x + threadIdx.x;
  if (e >= E) return;
  int d = dst[e];
  int pos = offs[d] + atomicAdd(&cursor[d], 1);
  eid[pos] = e;
}

// Pass 4: one wave per node. Phases: (A) per-head max, (B) per-head denom,
// (C) each lane owns channel `lane` (head = lane>>3) and accumulates a*v.
__global__ __launch_bounds__(256) void node_kernel(
    const float* __restrict__ v, const float* __restrict__ logits,
    const int* __restrict__ offs, const int* __restrict__ eid,
    float* __restrict__ out, int N) {
  __shared__ int sm_eid[4 * CAP];
  int tid = threadIdx.x;
  int wave = tid >> 6;
  int lane = tid & 63;
  int node = blockIdx.x * 4 + wave;
  int start = 0, deg = 0;
  if (node < N) {
    start = offs[node];
    deg = offs[node + 1] - start;
  }
  int nlds = min(deg, CAP);
  int* my = sm_eid + wave * CAP;
  for (int i = lane; i < nlds; i += 64) my[i] = eid[start + i];
  __syncthreads();
  if (node >= N) return;

  int j = lane >> 3;  // edge slot (phases A/B); also head for phase C
  int h = lane & 7;   // head (phases A/B)

  // Phase A: per-head running max over this node's edges.
  float m = -1e30f;
  for (int i = j; i < deg; i += 8) {
    int e = (i < CAP) ? my[i] : eid[start + i];
    m = fmaxf(m, logits[e * HH + h]);
  }
  m = fmaxf(m, __shfl_xor(m, 8, 64));
  m = fmaxf(m, __shfl_xor(m, 16, 64));
  m = fmaxf(m, __shfl_xor(m, 32, 64));

  // Phase B: per-head denom.
  float s = 0.f;
  for (int i = j; i < deg; i += 8) {
    int e = (i < CAP) ? my[i] : eid[start + i];
    s += __expf(logits[e * HH + h] - m);
  }
  s += __shfl_xor(s, 8, 64);
  s += __shfl_xor(s, 16, 64);
  s += __shfl_xor(s, 32, 64);

  // Redistribute (m, denom) from lane layout (h = lane&7) to channel layout
  // (head = lane>>3): lane `hc` (hc in [0,8)) holds head hc's reduced values.
  int hc = lane >> 3;
  float m_c = __shfl(m, hc, 64);
  float inv_c = 1.0f / __shfl(s, hc, 64);  // deg==0 -> inf, but loop C empty

  // Phase C: channel accumulation. Lane = channel in [0,64); 3 degree comps.
  float a0 = 0.f, a1 = 0.f, a2 = 0.f;
  for (int i = 0; i < deg; ++i) {
    int e = (i < CAP) ? my[i] : eid[start + i];
    float w = __expf(logits[e * HH + hc] - m_c) * inv_c;
    const float* vp = v + (size_t)e * 192 + lane * 3;
    a0 += w * vp[0];
    a1 += w * vp[1];
    a2 += w * vp[2];
  }
  float* op = out + (size_t)node * 192 + lane * 3;
  op[0] = a0;
  op[1] = a1;
  op[2] = a2;
}

extern "C" void kernel_launch(void* const* d_in, const int* in_sizes, int n_in,
                              void* d_out, int out_size, void* d_ws,
                              size_t ws_size, hipStream_t stream) {
  const float* v = (const float*)d_in[0];
  const float* k = (const float*)d_in[1];
  const float* q = (const float*)d_in[2];
  const int* dst = (const int*)d_in[3];
  float* out = (float*)d_out;

  const int E = in_sizes[3];            // 800000
  const int N = in_sizes[2] / (HH * TT);  // 50000

  // Workspace layout (256B-aligned):
  char* ws = (char*)d_ws;
  size_t off = 0;
  auto take = [&](size_t bytes) {
    void* p = ws + off;
    off += (bytes + 255) & ~(size_t)255;
    return p;
  };
  float* logits = (float*)take((size_t)E * HH * sizeof(float));  // 25.6 MB
  int* deg = (int*)take((size_t)N * sizeof(int));
  int* offs = (int*)take((size_t)(N + 1) * sizeof(int));
  int* cursor = (int*)take((size_t)N * sizeof(int));
  int* eid = (int*)take((size_t)E * sizeof(int));  // 3.2 MB

  hipMemsetAsync(deg, 0, (size_t)N * sizeof(int), stream);
  hipMemsetAsync(cursor, 0, (size_t)N * sizeof(int), stream);

  logits_kernel<<<(E * HH + 255) / 256, 256, 0, stream>>>(k, q, dst, logits,
                                                          deg, E);
  scan_kernel<<<1, 1024, 0, stream>>>(deg, offs, N);
  fill_kernel<<<(E + 255) / 256, 256, 0, stream>>>(dst, offs, cursor, eid, E);
  node_kernel<<<(N + 3) / 4, 256, 0, stream>>>(v, logits, offs, eid, out, N);
}

// Round 2
// 310.464 us; speedup vs baseline: 1.2607x; 1.2607x over previous
//
#include <hip/hip_runtime.h>

// v: [E, 64, 3] f32, k: [E, 8, 16] f32, q: [N, 8, 16] f32, dst: [E] i32
// out: [N, 64, 3] f32.  H=8 heads, T=16, 8 value channels/head, D=3.
#define HH 8
#define CAPL 128     // per-wave LDS edge cache (Poisson(16): P(deg>128) ~ 1e-58)
#define BSTRIDE 256  // bucket stride = max supported degree

static constexpr float SCALE = 0.08838834764831843f;  // 1/sqrt(8*16)

struct f3 {
  float x, y, z;
};  // align(4) so stride-12 casts are legal

__device__ __forceinline__ float dot16(const float* kp, float4 q0, float4 q1,
                                       float4 q2, float4 q3) {
  const float4* k4 = (const float4*)kp;
  float4 a = k4[0], b = k4[1], c = k4[2], d = k4[3];
  float acc = a.x * q0.x + a.y * q0.y + a.z * q0.z + a.w * q0.w;
  acc += b.x * q1.x + b.y * q1.y + b.z * q1.z + b.w * q1.w;
  acc += c.x * q2.x + c.y * q2.y + c.z * q2.z + c.w * q2.w;
  acc += d.x * q3.x + d.y * q3.y + d.z * q3.z + d.w * q3.w;
  return acc;
}

// Pass 1: bucket-append edge ids per destination node. No CSR scan needed.
__global__ __launch_bounds__(256) void fill_kernel(const int* __restrict__ dst,
                                                   int* __restrict__ cursor,
                                                   int* __restrict__ eid,
                                                   int E) {
  int e = blockIdx.x * blockDim.x + threadIdx.x;
  if (e >= E) return;
  int d = dst[e];
  int pos = atomicAdd(&cursor[d], 1);
  if (pos < BSTRIDE) eid[(size_t)d * BSTRIDE + pos] = e;
}

// Pass 2: one wave per node, fully fused logits -> softmax -> weighted sum.
// No __syncthreads anywhere: all LDS regions are wave-private.
__global__ __launch_bounds__(256) void node_kernel(
    const float* __restrict__ v, const float* __restrict__ k,
    const float* __restrict__ q, const int* __restrict__ cursor,
    const int* __restrict__ eid, float* __restrict__ out, int N) {
  __shared__ int eidL[4][CAPL];
  __shared__ float wL[4][CAPL * HH];  // logits, then exp values
  __shared__ float ovfL[4][HH];       // overflow-edge weights (never used)

  int tid = threadIdx.x;
  int wave = tid >> 6;
  int lane = tid & 63;
  int node = blockIdx.x * 4 + wave;
  if (node >= N) return;

  int deg = cursor[node];
  int nl = min(deg, CAPL);
  int nb = min(deg, BSTRIDE);
  const int* bucket = eid + (size_t)node * BSTRIDE;

  // Cache edge ids in LDS (wave-private).
  for (int i = lane; i < nl; i += 64) eidL[wave][i] = bucket[i];

  int h = lane & 7;   // head owned in phases 1-2
  int j = lane >> 3;  // edge-slot residue in phases 1-2

  // q row for head h -> registers (8 lanes share each 64B chunk: L1 broadcast)
  const float4* qq = (const float4*)(q + (size_t)node * 128 + h * 16);
  float4 q0 = qq[0], q1 = qq[1], q2 = qq[2], q3 = qq[3];

  // Phase 1: logits into LDS + per-(residue,head) running max.
  float m = -1e30f;
  for (int i = j; i < nl; i += 8) {
    int e = eidL[wave][i];
    float lg = dot16(k + (size_t)e * 128 + h * 16, q0, q1, q2, q3) * SCALE;
    wL[wave][i * 8 + h] = lg;
    m = fmaxf(m, lg);
  }
  for (int i = CAPL + j; i < nb; i += 8) {  // overflow (never in practice)
    int e = bucket[i];
    float lg = dot16(k + (size_t)e * 128 + h * 16, q0, q1, q2, q3) * SCALE;
    m = fmaxf(m, lg);
  }
  m = fmaxf(m, __shfl_xor(m, 8, 64));
  m = fmaxf(m, __shfl_xor(m, 16, 64));
  m = fmaxf(m, __shfl_xor(m, 32, 64));

  // Phase 2: exp in place + denom.
  float s = 0.f;
  for (int i = j; i < nl; i += 8) {
    float ex = __expf(wL[wave][i * 8 + h] - m);
    wL[wave][i * 8 + h] = ex;
    s += ex;
  }
  for (int i = CAPL + j; i < nb; i += 8) {  // overflow
    int e = bucket[i];
    float lg = dot16(k + (size_t)e * 128 + h * 16, q0, q1, q2, q3) * SCALE;
    s += __expf(lg - m);
  }
  s += __shfl_xor(s, 8, 64);
  s += __shfl_xor(s, 16, 64);
  s += __shfl_xor(s, 32, 64);
  float inv = (s > 0.f) ? 1.0f / s : 0.f;  // deg==0 -> write zeros, not NaN

  // Phase 3: channel accumulation. Lane owns channel `lane`, head hc=lane>>3.
  // One dwordx3 load per lane per edge: wave reads 768B contiguous.
  int hc = lane >> 3;
  float minv = __shfl(inv, hc, 64);  // lane hc holds head hc's denom
  float a0 = 0.f, a1 = 0.f, a2 = 0.f;
  for (int i = 0; i < nl; ++i) {
    int e = eidL[wave][i];
    float w = wL[wave][i * 8 + hc];  // 8-address broadcast, conflict-free
    f3 vv = *(const f3*)(v + (size_t)e * 192 + lane * 3);
    a0 += w * vv.x;
    a1 += w * vv.y;
    a2 += w * vv.z;
  }
  for (int i = CAPL; i < nb; ++i) {  // overflow (never in practice)
    int e = bucket[i];
    if (lane < 8) {  // lane<8 has h==lane, correct m for that head
      float lg = dot16(k + (size_t)e * 128 + lane * 16, q0, q1, q2, q3) * SCALE;
      ovfL[wave][lane] = __expf(lg - m);
    }
    float w = ovfL[wave][hc];  // same-wave LDS RAW: lgkmcnt ordering
    f3 vv = *(const f3*)(v + (size_t)e * 192 + lane * 3);
    a0 += w * vv.x;
    a1 += w * vv.y;
    a2 += w * vv.z;
  }
  a0 *= minv;
  a1 *= minv;
  a2 *= minv;

  f3* op = (f3*)(out + (size_t)node * 192 + lane * 3);
  op->x = a0;
  op->y = a1;
  op->z = a2;
}

extern "C" void kernel_launch(void* const* d_in, const int* in_sizes, int n_in,
                              void* d_out, int out_size, void* d_ws,
                              size_t ws_size, hipStream_t stream) {
  const float* v = (const float*)d_in[0];
  const float* k = (const float*)d_in[1];
  const float* q = (const float*)d_in[2];
  const int* dst = (const int*)d_in[3];
  float* out = (float*)d_out;

  const int E = in_sizes[3];              // 800000
  const int N = in_sizes[2] / (HH * 16);  // 50000

  char* ws = (char*)d_ws;
  int* cursor = (int*)ws;                               // N ints
  int* eid = (int*)(ws + (((size_t)N * 4 + 255) & ~(size_t)255));  // N*BSTRIDE

  hipMemsetAsync(cursor, 0, (size_t)N * sizeof(int), stream);
  fill_kernel<<<(E + 255) / 256, 256, 0, stream>>>(dst, cursor, eid, E);
  node_kernel<<<(N + 3) / 4, 256, 0, stream>>>(v, k, q, cursor, eid, out, N);
}